// Round 1
// baseline (275376.904 us; speedup 1.0000x reference)
//
#include <hip/hip_runtime.h>
#include <math.h>

#define NN 256
#define HH 64
#define SDIM 260

__device__ __forceinline__ float sigm(float x) { return 1.0f / (1.0f + expf(-x)); }

// Pout = I + (h/div) * A    (elementwise; h = tev[1]-tev[0])
__global__ void k_affine(const float* __restrict__ A, float* __restrict__ Pout,
                         const float* __restrict__ tev, int div)
{
    int i = blockIdx.x, j = threadIdx.x;
    double h = (double)tev[1] - (double)tev[0];
    double v = (i == j ? 1.0 : 0.0) + (h / (double)div) * (double)A[i * NN + j];
    Pout[i * NN + j] = (float)v;
}

// Pout = I + (h/div) * A @ Pin   (fp64 accumulate)
__global__ void k_gemm(const float* __restrict__ A, const float* __restrict__ Pin,
                       float* __restrict__ Pout, const float* __restrict__ tev, int div)
{
    int i = blockIdx.x, j = threadIdx.x;
    double h = (double)tev[1] - (double)tev[0];
    const float* Ar = A + i * NN;
    double acc = 0.0;
    for (int k = 0; k < NN; ++k) acc += (double)Ar[k] * (double)Pin[k * NN + j];
    double v = (i == j ? 1.0 : 0.0) + (h / (double)div) * acc;
    Pout[i * NN + j] = (float)v;
}

// gq = [g0 | g1 | g2 | g3 | q], each 256 floats.
// g0=(h/6)B0, g1=(h^2/6)A B0, g2=(h^3/12)A^2 B0, g3=(h^4/24)A^3 B0
// q = h*bh + (h^2/2)A bh + (h^3/6)A^2 bh + (h^4/24)A^3 bh,  bh = B[:,1:]@heat
__global__ void k_prep_vec(const float* __restrict__ A, const float* __restrict__ B,
                           const float* __restrict__ cooling, const float* __restrict__ tev,
                           float* __restrict__ gq)
{
    __shared__ float heat[NN];
    __shared__ float vin[NN];
    int t = threadIdx.x; // 256 threads
    double h = (double)tev[1] - (double)tev[0];
    heat[t] = (t < NN - 2) ? 500.0f * sigm(cooling[t]) : 0.0f;
    __syncthreads();
    float B0 = B[t * (NN - 1)];
    double bh = 0.0;
    for (int j = 0; j < NN - 2; ++j) bh += (double)B[t * (NN - 1) + 1 + j] * (double)heat[j];
    // chain for B0
    vin[t] = B0; __syncthreads();
    double v1 = 0.0; for (int k = 0; k < NN; ++k) v1 += (double)A[t * NN + k] * (double)vin[k];
    __syncthreads(); vin[t] = (float)v1; __syncthreads();
    double v2 = 0.0; for (int k = 0; k < NN; ++k) v2 += (double)A[t * NN + k] * (double)vin[k];
    __syncthreads(); vin[t] = (float)v2; __syncthreads();
    double v3 = 0.0; for (int k = 0; k < NN; ++k) v3 += (double)A[t * NN + k] * (double)vin[k];
    __syncthreads();
    // chain for bh
    vin[t] = (float)bh; __syncthreads();
    double u1 = 0.0; for (int k = 0; k < NN; ++k) u1 += (double)A[t * NN + k] * (double)vin[k];
    __syncthreads(); vin[t] = (float)u1; __syncthreads();
    double u2 = 0.0; for (int k = 0; k < NN; ++k) u2 += (double)A[t * NN + k] * (double)vin[k];
    __syncthreads(); vin[t] = (float)u2; __syncthreads();
    double u3 = 0.0; for (int k = 0; k < NN; ++k) u3 += (double)A[t * NN + k] * (double)vin[k];

    gq[t]        = (float)((h / 6.0) * (double)B0);
    gq[256 + t]  = (float)((h * h / 6.0) * v1);
    gq[512 + t]  = (float)((h * h * h / 12.0) * v2);
    gq[768 + t]  = (float)((h * h * h * h / 24.0) * v3);
    gq[1024 + t] = (float)(h * bh + (h * h / 2.0) * u1 + (h * h * h / 6.0) * u2
                           + (h * h * h * h / 24.0) * u3);
}

__device__ __forceinline__ float interp1(float x, const float* __restrict__ ts,
                                         const float* __restrict__ vs, int n)
{
    // np.interp semantics: i = clip(searchsorted(ts, x, side='right'), 1, n-1)
    int lo = 0, hi = n;
    while (lo < hi) { int mid = (lo + hi) >> 1; if (ts[mid] <= x) lo = mid + 1; else hi = mid; }
    int i = lo; if (i < 1) i = 1; if (i > n - 1) i = n - 1;
    float xim = ts[i - 1], xi = ts[i];
    float fim = vs[i - 1], fi = vs[i];
    return fim + (x - xim) / (xi - xim) * (fi - fim);
}

// per-step time data: td[k][0..7] = {S0,S1,S2,S3, sinD,cosD,sinW,cosW}
__global__ void k_time(const float* __restrict__ tev, const float* __restrict__ tts,
                       const float* __restrict__ tvals, float* __restrict__ td,
                       int T, int ntout)
{
    int k = blockIdx.x * blockDim.x + threadIdx.x;
    if (k >= T) return;
    float t0 = tev[0];
    float dtf = tev[1] - t0;
    float t = tev[k] - t0;
    const float cD = (float)(2.0 * M_PI / 86400.0);
    const float cW = (float)(2.0 * M_PI / 604800.0);
    float f0 = (float)sin((double)(t * cD));
    float f1 = (float)cos((double)(t * cD));
    float f2 = (float)sin((double)(t * cW));
    float f3 = (float)cos((double)(t * cW));
    float To1 = interp1(t + t0, tts, tvals, ntout);
    float To2 = interp1((t + 0.5f * dtf) + t0, tts, tvals, ntout);
    float To4 = interp1((t + dtf) + t0, tts, tvals, ntout);
    size_t o = (size_t)k * 8;
    td[o + 0] = To1 + 4.0f * To2 + To4;
    td[o + 1] = To1 + 2.0f * To2;
    td[o + 2] = To1 + To2;
    td[o + 3] = To1;
    td[o + 4] = f0; td[o + 5] = f1; td[o + 6] = f2; td[o + 7] = f3;
}

// Sequential integrator: 1 block, 512 threads, R held in VGPRs (128/thread).
__global__ __launch_bounds__(512, 2) void k_main(
    const float* __restrict__ tdata, const float* __restrict__ Rm,
    const float* __restrict__ gq, const float* __restrict__ w1g,
    const float* __restrict__ b1g, const float* __restrict__ w2g,
    float* __restrict__ out, int T)
{
    __shared__ __align__(16) float xbuf[NN];
    __shared__ __align__(16) float sbuf[288];   // s (260) + zero pad
    __shared__ float hid[HH];
    __shared__ float part[2][NN];
    __shared__ float aS;
    __shared__ float td[2][8];

    const int t = threadIdx.x;
    const int r = t & 255;
    const int seg = t >> 8;       // 0..1 (half of the row)
    const int jr = t >> 3;        // policy row 0..63
    const int c0 = t & 7;         // policy column chunk

    // R rows -> registers
    float Rreg[128];
    {
        const float* src = Rm + (size_t)r * NN + seg * 128;
        #pragma unroll
        for (int i = 0; i < 32; ++i) {
            float4 v = reinterpret_cast<const float4*>(src)[i];
            Rreg[4 * i + 0] = v.x; Rreg[4 * i + 1] = v.y;
            Rreg[4 * i + 2] = v.z; Rreg[4 * i + 3] = v.w;
        }
    }
    // w1 -> registers (36-col chunk per thread, zero-padded)
    float w1reg[36];
    #pragma unroll
    for (int i = 0; i < 36; ++i) {
        int c = c0 * 36 + i;
        w1reg[i] = (c < SDIM) ? w1g[jr * SDIM + c] : 0.0f;
    }
    float b1r = b1g[jr];
    float w2r = (t < HH) ? w2g[t] : 0.0f;
    float g0r = gq[r], g1r = gq[256 + r], g2r = gq[512 + r], g3r = gq[768 + r];
    float qr = gq[1024 + r];

    if (t < NN) xbuf[t] = 26.0f;                    // iv
    if (t >= 260 && t < 288) sbuf[t] = 0.0f;        // pad for over-read
    if (t < 8) td[0][t] = tdata[t];
    __syncthreads();

    for (int k = 0; k < T; ++k) {
        const int cur = k & 1, nxt = cur ^ 1;
        // prefetch next step's time data (issue early, write to LDS late)
        float tdp = 0.0f;
        if (t >= 504) { int kk = k + 1; if (kk < T) tdp = tdata[(size_t)kk * 8 + (t - 504)]; }
        // Phase 0: emit traj + build policy input
        if (t < NN) {
            float xv = xbuf[t];
            out[(size_t)k * NN + t] = xv;
            sbuf[t] = (xv - 23.359f) / 1.41f;
        } else if (t < 260) {
            sbuf[t] = td[cur][t - 252];             // features at td[4..7]
        }
        __syncthreads();
        // Phase 1: hidden = tanh(w1 @ s + b1)
        float hs = 0.0f;
        {
            const float4* sb4 = reinterpret_cast<const float4*>(sbuf + c0 * 36);
            #pragma unroll
            for (int i = 0; i < 9; ++i) {
                float4 sv = sb4[i];
                hs += w1reg[4 * i + 0] * sv.x + w1reg[4 * i + 1] * sv.y
                    + w1reg[4 * i + 2] * sv.z + w1reg[4 * i + 3] * sv.w;
            }
        }
        hs += __shfl_xor(hs, 1);
        hs += __shfl_xor(hs, 2);
        hs += __shfl_xor(hs, 4);
        if (c0 == 0) hid[jr] = tanhf(hs + b1r);
        __syncthreads();
        // Phase 2+3: matvec partials (R @ x) and action a = sigmoid(w2 . hid)
        float a0 = 0.f, a1 = 0.f, a2 = 0.f, a3 = 0.f;
        {
            const float4* xb4 = reinterpret_cast<const float4*>(xbuf) + seg * 32;
            #pragma unroll
            for (int i = 0; i < 32; ++i) {
                float4 xv = xb4[i];
                a0 += Rreg[4 * i + 0] * xv.x;
                a1 += Rreg[4 * i + 1] * xv.y;
                a2 += Rreg[4 * i + 2] * xv.z;
                a3 += Rreg[4 * i + 3] * xv.w;
            }
        }
        if (t < HH) {
            float v = w2r * hid[t];
            v += __shfl_xor(v, 1); v += __shfl_xor(v, 2); v += __shfl_xor(v, 4);
            v += __shfl_xor(v, 8); v += __shfl_xor(v, 16); v += __shfl_xor(v, 32);
            if (t == 0) aS = sigm(v);
        }
        part[seg][r] = (a0 + a1) + (a2 + a3);
        __syncthreads();
        // Phase 4: x_new = R x + S.g - a q ; stage next td
        if (t < NN) {
            float S0 = td[cur][0], S1 = td[cur][1], S2 = td[cur][2], S3 = td[cur][3];
            float y = part[0][t] + part[1][t];
            float xn = y + S0 * g0r + S1 * g1r + S2 * g2r + S3 * g3r - aS * qr;
            xbuf[t] = xn;
        }
        if (t >= 504) td[nxt][t - 504] = tdp;
        __syncthreads();
    }
}

extern "C" void kernel_launch(void* const* d_in, const int* in_sizes, int n_in,
                              void* d_out, int out_size, void* d_ws, size_t ws_size,
                              hipStream_t stream)
{
    (void)n_in; (void)out_size; (void)ws_size;
    const float* tev     = (const float*)d_in[0];
    const float* A       = (const float*)d_in[1];
    const float* B       = (const float*)d_in[2];
    const float* cooling = (const float*)d_in[3];
    const float* w1      = (const float*)d_in[4];
    const float* b1      = (const float*)d_in[5];
    const float* w2      = (const float*)d_in[6];
    const float* tts     = (const float*)d_in[7];
    const float* tvals   = (const float*)d_in[8];
    const int T     = in_sizes[0];
    const int ntout = in_sizes[7];

    float* out = (float*)d_out;
    float* ws  = (float*)d_ws;
    float* R   = ws;                       // 65536
    float* gq  = ws + 65536;               // 1280
    float* td  = ws + 65536 + 1280;        // T*8
    // GEMM ping-pong scratch lives in d_out (fully rewritten by k_main afterwards)
    float* P1 = out;
    float* P2 = out + 65536;

    hipLaunchKernelGGL(k_affine, dim3(256), dim3(256), 0, stream, A, P1, tev, 4);
    hipLaunchKernelGGL(k_gemm,   dim3(256), dim3(256), 0, stream, A, P1, P2, tev, 3);
    hipLaunchKernelGGL(k_gemm,   dim3(256), dim3(256), 0, stream, A, P2, P1, tev, 2);
    hipLaunchKernelGGL(k_gemm,   dim3(256), dim3(256), 0, stream, A, P1, R,  tev, 1);
    hipLaunchKernelGGL(k_prep_vec, dim3(1), dim3(256), 0, stream, A, B, cooling, tev, gq);
    hipLaunchKernelGGL(k_time, dim3((T + 255) / 256), dim3(256), 0, stream,
                       tev, tts, tvals, td, T, ntout);
    hipLaunchKernelGGL(k_main, dim3(1), dim3(512), 0, stream,
                       td, R, gq, w1, b1, w2, out, T);
}